// Round 5
// baseline (184.575 us; speedup 1.0000x reference)
//
#include <hip/hip_runtime.h>

typedef _Float16 half2v __attribute__((ext_vector_type(2)));
typedef _Float16 half4v __attribute__((ext_vector_type(4)));
typedef _Float16 half8v __attribute__((ext_vector_type(8)));
typedef float   float4v __attribute__((ext_vector_type(4)));

#define INC     16
#define OUTC    16
#define EFN     13
#define HIDC    32
#define EPB     128    // edges per (single-wave) block
#define MAXSPAN 80     // node-range per 128-edge block (mean ~8; vast headroom)

union H8 { half8v v; half2v h2[4]; };

// ---------------------------------------------------------------------------
// One-time prep:
//   blocks 0..31   : pack W2 into the f16 B-fragment image (kappa-permuted,
//                    layout half[(t*64+lane)*8 + j]).
//   blocks 32..end : convert x (N,16) f32 -> f16 rows (same (_Float16) cast
//                    the edge kernel used, so results are bit-identical).
// ---------------------------------------------------------------------------
__global__ __launch_bounds__(256) void prep(
    const float* __restrict__ W2,
    const float* __restrict__ x,
    _Float16*    __restrict__ wsB,
    _Float16*    __restrict__ wsXh,
    int nh)                                  // N*16
{
    const int b = blockIdx.x;
    if (b < 32) {
        const int i = b * 256 + threadIdx.x;   // 0..8191 half index
        const int j = i & 7;
        const int l = (i >> 3) & 63;
        const int t = i >> 9;
        const int q = l >> 4, n = l & 15;
        const int kk = (j < 4) ? (q * 4 + j) : (16 + q * 4 + (j & 3));
        wsB[i] = (_Float16)W2[kk * 256 + t * 16 + n];
    } else {
        const int i = (b - 32) * 256 + threadIdx.x;   // half8 index
        if (i * 8 < nh) {
            const float4 v0 = ((const float4*)x)[i * 2];
            const float4 v1 = ((const float4*)x)[i * 2 + 1];
            half8v h;
            h[0] = (_Float16)v0.x; h[1] = (_Float16)v0.y;
            h[2] = (_Float16)v0.z; h[3] = (_Float16)v0.w;
            h[4] = (_Float16)v1.x; h[5] = (_Float16)v1.y;
            h[6] = (_Float16)v1.z; h[7] = (_Float16)v1.w;
            *(half8v*)(wsXh + (size_t)i * 8) = h;
        }
    }
}

// ---------------------------------------------------------------------------
// Single-wave MFMA edge kernel, batched-MLP version.
//   One wave = one block = 128 edges = 8 statically-unrolled tiles of 16.
//   Load schedule (pinned with sched_barrier so hipcc can't sink it):
//     - all 8 ef fragments issued upfront   (HBM stream, depth-8 prefetch)
//     - all 8 idxn tile-vectors upfront     (kills idxn->x chain)
//     - W2 B-fragments (64 VGPR) upfront    (L2-hot)
//     - x rows in a 2-deep rolling pipeline (static slots, no scratch)
//   Compute per tile: 2 x mfma_16x16x16_f16 (h) + 17 x mfma_16x16x32_f16.
//   Sorted idxd => tiny per-block LDS bins; interior nodes get deg-division
//   fused; boundary runs land in per-block ws slots for the fixup kernel.
// ---------------------------------------------------------------------------
__global__ __launch_bounds__(64, 3) void edge_kernel(
    const _Float16* __restrict__ xh,       // (N,16) f16 (prebuilt)
    const float* __restrict__ edgefeats,   // (E,13)
    const float* __restrict__ W1,          // (13,32)
    const float* __restrict__ b1,          // (32,)
    const float* __restrict__ b2,          // (256,)
    const int*   __restrict__ idxn,        // (E,)
    const int*   __restrict__ idxd,        // (E,) sorted
    const float* __restrict__ degs,        // (N,)
    const _Float16* __restrict__ wsB,      // (8192,) prebuilt B image
    float*       __restrict__ out,         // (N,16) final output
    float*       __restrict__ wsPfirst,    // (nblocks,16)
    float*       __restrict__ wsPlast,     // (nblocks,16)
    int*         __restrict__ wsMeta,      // (nblocks,4)
    int E)
{
    __shared__ float lacc[MAXSPAN * OUTC];          // 5 KB bins
    __shared__ __align__(4) unsigned char su[EPB];  // 128 B idxd offsets

    const int lane = threadIdx.x;    // 0..63, one wave
    const int n    = lane & 15;
    const int q    = lane >> 4;

    const long b0   = (long)blockIdx.x * EPB;
    const long bEnd = (b0 + EPB < (long)E) ? (b0 + EPB) : (long)E;
    const int  d_lo = idxd[b0];
    const int  d_hi = idxd[bEnd - 1];
    const int  span = d_hi - d_lo;   // < MAXSPAN by construction

    const long Em1 = (long)E - 1;
    const int  f0  = (q < 3) ? (q * 4) : 9;  // q==3: load feats 9..12, keep .w

    // ---- batch-issue: all 8 ef fragments (HBM stream -> deepest prefetch) ----
    float4 efr[8];
    #pragma unroll
    for (int t = 0; t < 8; ++t) {
        long e = b0 + t * 16 + n;
        if (e > Em1) e = Em1;
        efr[t] = *(const float4*)(edgefeats + (size_t)e * EFN + f0);
    }

    // ---- batch-issue: all 8 idxn tile-vectors ----
    int node[8];
    #pragma unroll
    for (int t = 0; t < 8; ++t) {
        long e = b0 + t * 16 + n;
        node[t] = idxn[(e <= Em1) ? e : Em1];
    }

    // ---- W2 B-fragments: 16 x dwordx4 from the L2-hot image -> 64 VGPRs ----
    H8 bfr[16];
    #pragma unroll
    for (int t = 0; t < 16; ++t)
        bfr[t].v = *(const half8v*)(wsB + ((size_t)(t * 64 + lane) * 8));

    // ---- zero bins, stage idxd-offset bytes ----
    #pragma unroll
    for (int it = 0; it < MAXSPAN * OUTC / 64; ++it) lacc[lane + it * 64] = 0.0f;
    {
        const int i2 = lane * 2;
        long e0 = b0 + i2, e1 = b0 + i2 + 1;
        if (e0 > Em1) e0 = Em1;
        if (e1 > Em1) e1 = Em1;
        const unsigned u0 = (unsigned)(idxd[e0] - d_lo);
        const unsigned u1 = (unsigned)(idxd[e1] - d_lo);
        *(unsigned short*)&su[i2] = (unsigned short)(u0 | (u1 << 8));
    }

    // ---- per-lane constants: W1^T A-fragments, b1 C-init, b2 B-fragment ----
    half4v a1, a2;
    float4v c1, c2;
    #pragma unroll
    for (int jj = 0; jj < 4; ++jj) {
        const int f = q * 4 + jj;
        const bool ok = (f < EFN);
        a1[jj] = ok ? (_Float16)W1[f * HIDC + n]      : (_Float16)0.f;
        a2[jj] = ok ? (_Float16)W1[f * HIDC + 16 + n] : (_Float16)0.f;
        c1[jj] = b1[q * 4 + jj];
        c2[jj] = b1[16 + q * 4 + jj];
    }
    half8v bfragB2;
    #pragma unroll
    for (int j = 0; j < 8; ++j) {
        _Float16 val = (_Float16)0.f;
        if (q < 2) val = (_Float16)b2[(q * 8 + j) * 16 + n];
        bfragB2[j] = val;
    }

    __syncthreads();   // single wave: cheap fence; orders su/lacc

    // ---- x-row pipeline prologue: 2-deep slots (static indices only) ----
    half8v pxa[2], pxb[2];
    pxa[0] = *(const half8v*)(xh + (size_t)node[0] * INC);
    pxb[0] = *(const half8v*)(xh + (size_t)node[0] * INC + 8);
    pxa[1] = *(const half8v*)(xh + (size_t)node[1] * INC);
    pxb[1] = *(const half8v*)(xh + (size_t)node[1] * INC + 8);
    __builtin_amdgcn_sched_barrier(0);   // pin loads above this point

    // ---- fully-unrolled 8-tile loop (pad tiles contribute 0 to the bins) ----
    #pragma unroll
    for (int t16 = 0; t16 < 8; ++t16) {
        const int cur = t16 & 1;           // compile-time after unroll
        const long base = b0 + (long)t16 * 16;
        const bool vM   = (base + n < (long)E);

        // grab current tile's x rows, then reuse the slot for tile t16+2
        const half8v xA = pxa[cur];
        const half8v xB = pxb[cur];
        if (t16 + 2 < 8) {
            pxa[cur] = *(const half8v*)(xh + (size_t)node[t16 + 2] * INC);
            pxb[cur] = *(const half8v*)(xh + (size_t)node[t16 + 2] * INC + 8);
        }
        __builtin_amdgcn_sched_barrier(0); // keep the issue ahead of compute

        const unsigned u4 = *(const unsigned*)&su[t16 * 16 + q * 4];

        // ---- compute tile t16 from resident registers ----
        H8 sa, sb_;
        sa.v = xA; sb_.v = xB;
        const half2v zz = {(_Float16)0.f, (_Float16)0.f};
        half2v selh[8];
        #pragma unroll
        for (int i = 0; i < 4; ++i) {
            selh[i]     = vM ? sa.h2[i]  : zz;
            selh[4 + i] = vM ? sb_.h2[i] : zz;
        }

        half4v efB;
        if (q < 3) {
            efB[0] = (_Float16)efr[t16].x; efB[1] = (_Float16)efr[t16].y;
            efB[2] = (_Float16)efr[t16].z; efB[3] = (_Float16)efr[t16].w;
        } else {
            efB[0] = (_Float16)efr[t16].w; efB[1] = (_Float16)0.f;
            efB[2] = (_Float16)0.f;        efB[3] = (_Float16)0.f;
        }

        // h^T = relu(W1^T @ EF^T + b1): lane holds hids {q*4+r, 16+q*4+r}
        const float4v hf1 = __builtin_amdgcn_mfma_f32_16x16x16f16(a1, efB, c1, 0, 0, 0);
        const float4v hf2 = __builtin_amdgcn_mfma_f32_16x16x16f16(a2, efB, c2, 0, 0, 0);

        H8 hu;   // hu half j <-> hid kappa(q,j); matches prep's image
        #pragma unroll
        for (int r = 0; r < 2; ++r) {
            half2v t1 = {(_Float16)fmaxf(hf1[2*r], 0.f), (_Float16)fmaxf(hf1[2*r+1], 0.f)};
            half2v t2 = {(_Float16)fmaxf(hf2[2*r], 0.f), (_Float16)fmaxf(hf2[2*r+1], 0.f)};
            hu.h2[r]     = t1;
            hu.h2[2 + r] = t2;
        }

        // ---- 16 W2 steps (B in registers) + 1 b2 step ----
        float4v acc = {0.f, 0.f, 0.f, 0.f};
        #pragma unroll
        for (int t = 0; t < 16; ++t) {
            _Float16 sv = (t & 1) ? selh[t >> 1][1] : selh[t >> 1][0];
            half2v sb = {sv, sv};
            H8 a;
            a.h2[0] = sb * hu.h2[0];
            a.h2[1] = sb * hu.h2[1];
            a.h2[2] = sb * hu.h2[2];
            a.h2[3] = sb * hu.h2[3];
            acc = __builtin_amdgcn_mfma_f32_16x16x32_f16(a.v, bfr[t].v, acc, 0, 0, 0);
        }
        {
            H8 a;
            #pragma unroll
            for (int j2 = 0; j2 < 4; ++j2) {
                a.h2[j2] = (q < 2) ? selh[q * 4 + j2] : zz;
            }
            acc = __builtin_amdgcn_mfma_f32_16x16x32_f16(a.v, bfragB2, acc, 0, 0, 0);
        }

        // ---- scatter into LDS bins; combine when the 4-edge run is one node
        const unsigned rep = (u4 & 0xffu) * 0x01010101u;
        if (u4 == rep) {
            atomicAdd(&lacc[(u4 & 0xffu) * OUTC + n],
                      acc[0] + acc[1] + acc[2] + acc[3]);
        } else {
            #pragma unroll
            for (int r = 0; r < 4; ++r)
                atomicAdd(&lacc[((u4 >> (8 * r)) & 0xffu) * OUTC + n], acc[r]);
        }
    }

    __syncthreads();   // order LDS atomics before the flush reads

    // ---- flush: fuse deg-division for complete segments -> out;
    //      boundary partials -> ws slots (no global atomics anywhere) ----
    const bool first_starts = (b0 == 0)        || (idxd[b0 - 1] != d_lo);
    const bool last_ends    = (bEnd == (long)E) || (idxd[bEnd]   != d_hi);

    for (int i = lane; i < (span + 1) * OUTC; i += 64) {
        const int u = i >> 4;
        const int o = i & 15;
        const int v = d_lo + u;
        const float bin = lacc[u * OUTC + o];
        const bool starts = (u > 0)    || first_starts;
        const bool ends   = (u < span) || last_ends;
        if (starts && ends) {
            const float dg = degs[v];
            out[(size_t)v * OUTC + o] = (dg > 0.0f) ? bin / dg : 0.0f;
        } else if (!starts) {
            wsPfirst[(size_t)blockIdx.x * OUTC + o] = bin;
        } else {
            wsPlast[(size_t)blockIdx.x * OUTC + o] = bin;
        }
    }
    if (lane == 0) {
        wsMeta[blockIdx.x * 4 + 0] = d_hi;
        wsMeta[blockIdx.x * 4 + 1] = last_ends ? 1 : 0;
        wsMeta[blockIdx.x * 4 + 2] =
            (((span > 0) || first_starts) && !last_ends) ? 1 : 0;
    }
}

// ---------------------------------------------------------------------------
// Fixup: (a) owner blocks walk their open run across following blocks and
// write the finalized node; (b) deg-0 nodes get zeros.
// ---------------------------------------------------------------------------
__global__ __launch_bounds__(256) void fixup_kernel(
    const float* __restrict__ degs,
    float*       __restrict__ out,
    const float* __restrict__ wsPfirst,
    const float* __restrict__ wsPlast,
    const int*   __restrict__ wsMeta,
    int N, int nblocks)
{
    const int t = blockIdx.x * 256 + threadIdx.x;

    if (t < nblocks && wsMeta[t * 4 + 2]) {
        const int v = wsMeta[t * 4 + 0];
        float tot[OUTC];
        #pragma unroll
        for (int o = 0; o < OUTC; ++o) tot[o] = wsPlast[(size_t)t * OUTC + o];
        for (int j = t + 1; j < nblocks; ++j) {
            #pragma unroll
            for (int o = 0; o < OUTC; ++o) tot[o] += wsPfirst[(size_t)j * OUTC + o];
            if (wsMeta[j * 4 + 0] != v || wsMeta[j * 4 + 1]) break;
        }
        const float dg = degs[v];   // v has edges => dg > 0
        #pragma unroll
        for (int o = 0; o < OUTC; ++o) out[(size_t)v * OUTC + o] = tot[o] / dg;
    }

    if (t < N && degs[t] == 0.0f) {
        float4* op = (float4*)(out + (size_t)t * OUTC);
        const float4 z = make_float4(0, 0, 0, 0);
        op[0] = z; op[1] = z; op[2] = z; op[3] = z;
    }
}

// ---------------------------------------------------------------------------
extern "C" void kernel_launch(void* const* d_in, const int* in_sizes, int n_in,
                              void* d_out, int out_size, void* d_ws, size_t ws_size,
                              hipStream_t stream)
{
    const float* x         = (const float*)d_in[0];
    const float* edgefeats = (const float*)d_in[1];
    const float* W1        = (const float*)d_in[2];
    const float* b1        = (const float*)d_in[3];
    const float* W2        = (const float*)d_in[4];
    const float* b2        = (const float*)d_in[5];
    const int*   idxn      = (const int*)d_in[6];
    const int*   idxd      = (const int*)d_in[7];
    const float* degs      = (const float*)d_in[8];

    const int E = in_sizes[6];
    const int N = in_sizes[8];
    const int nblocks = (E + EPB - 1) / EPB;
    const int nh = N * INC;

    // workspace layout: wsB (16 KB) | wsXh (N*16 f16) | ws slots
    _Float16* wsB  = (_Float16*)d_ws;
    _Float16* wsXh = (_Float16*)((char*)d_ws + 16384);
    size_t xh_bytes = ((size_t)nh * 2 + 255) & ~(size_t)255;
    float* wsPfirst = (float*)((char*)d_ws + 16384 + xh_bytes);
    float* wsPlast  = wsPfirst + (size_t)nblocks * OUTC;
    int*   wsMeta   = (int*)(wsPlast + (size_t)nblocks * OUTC);

    const int xhblocks = (nh / 8 + 255) / 256;
    prep<<<32 + xhblocks, 256, 0, stream>>>(W2, x, wsB, wsXh, nh);

    edge_kernel<<<nblocks, 64, 0, stream>>>(wsXh, edgefeats, W1, b1, b2,
                                            idxn, idxd, degs, wsB, (float*)d_out,
                                            wsPfirst, wsPlast, wsMeta, E);

    const int fthreads = (N > nblocks) ? N : nblocks;
    fixup_kernel<<<(fthreads + 255) / 256, 256, 0, stream>>>(
        degs, (float*)d_out, wsPfirst, wsPlast, wsMeta, N, nblocks);
}

// Round 6
// 158.701 us; speedup vs baseline: 1.1630x; 1.1630x over previous
//
#include <hip/hip_runtime.h>

typedef _Float16 half2v __attribute__((ext_vector_type(2)));
typedef _Float16 half4v __attribute__((ext_vector_type(4)));
typedef _Float16 half8v __attribute__((ext_vector_type(8)));
typedef float   float4v __attribute__((ext_vector_type(4)));

#define INC     16
#define OUTC    16
#define EFN     13
#define HIDC    32
#define EPB     128    // edges per (single-wave) block
#define MAXSPAN 80     // node-range per 128-edge block (mean ~8; vast headroom)

#define GLOBAL_AS __attribute__((address_space(1)))
#define LDS_AS    __attribute__((address_space(3)))

union H8 { half8v v; half2v h2[4]; };

// ---------------------------------------------------------------------------
// One-time prep:
//   blocks 0..31   : pack W2 into the f16 B-fragment image (kappa-permuted,
//                    layout half[(t*64+lane)*8 + j]).
//   blocks 32..end : convert x (N,16) f32 -> f16 rows (same (_Float16) cast
//                    the edge kernel uses, so results are bit-identical).
// ---------------------------------------------------------------------------
__global__ __launch_bounds__(256) void prep(
    const float* __restrict__ W2,
    const float* __restrict__ x,
    _Float16*    __restrict__ wsB,
    _Float16*    __restrict__ wsXh,
    int nh)                                  // N*16
{
    const int b = blockIdx.x;
    if (b < 32) {
        const int i = b * 256 + threadIdx.x;   // 0..8191 half index
        const int j = i & 7;
        const int l = (i >> 3) & 63;
        const int t = i >> 9;
        const int q = l >> 4, n = l & 15;
        const int kk = (j < 4) ? (q * 4 + j) : (16 + q * 4 + (j & 3));
        wsB[i] = (_Float16)W2[kk * 256 + t * 16 + n];
    } else {
        const int i = (b - 32) * 256 + threadIdx.x;   // half8 index
        if (i * 8 < nh) {
            const float4 v0 = ((const float4*)x)[i * 2];
            const float4 v1 = ((const float4*)x)[i * 2 + 1];
            half8v h;
            h[0] = (_Float16)v0.x; h[1] = (_Float16)v0.y;
            h[2] = (_Float16)v0.z; h[3] = (_Float16)v0.w;
            h[4] = (_Float16)v1.x; h[5] = (_Float16)v1.y;
            h[6] = (_Float16)v1.z; h[7] = (_Float16)v1.w;
            *(half8v*)(wsXh + (size_t)i * 8) = h;
        }
    }
}

// ---------------------------------------------------------------------------
// Single-wave MFMA edge kernel, async-staged version.
//   One wave = one block = 128 edges = 8 statically-unrolled tiles of 16.
//   The block's edgefeat slab (6656 B), idxn slab (512 B) and idxd slab
//   (512 B) are CONTIGUOUS in global, so they are staged with 9 async
//   global_load_lds ops issued upfront: the wave's whole HBM stream is in
//   flight immediately, at zero VGPR cost (the register-batched variant of
//   this spilled: R5, WRITE_SIZE 53 MB).  The only VMEM left in the loop is
//   the x-gather, software-pipelined 2-deep with static slot names (full
//   unroll => no dynamic indexing => no scratch).  W2 B-fragments live in
//   64 VGPRs (L2-hot image).  Sorted idxd => tiny per-block LDS bins;
//   interior nodes get deg-division fused; boundary runs go to ws slots.
// ---------------------------------------------------------------------------
__global__ __launch_bounds__(64, 3) void edge_kernel(
    const _Float16* __restrict__ xh,       // (N,16) f16 (prebuilt)
    const float* __restrict__ edgefeats,   // (E,13)
    const float* __restrict__ W1,          // (13,32)
    const float* __restrict__ b1,          // (32,)
    const float* __restrict__ b2,          // (256,)
    const int*   __restrict__ idxn,        // (E,)
    const int*   __restrict__ idxd,        // (E,) sorted
    const float* __restrict__ degs,        // (N,)
    const _Float16* __restrict__ wsB,      // (8192,) prebuilt B image
    float*       __restrict__ out,         // (N,16) final output
    float*       __restrict__ wsPfirst,    // (nblocks,16)
    float*       __restrict__ wsPlast,     // (nblocks,16)
    int*         __restrict__ wsMeta,      // (nblocks,4)
    int E)
{
    __shared__ __align__(16) float sEF[EPB * EFN];   // 6656 B, global-slab layout
    __shared__ __align__(16) int   sidxn[EPB];       // 512 B
    __shared__ __align__(16) int   sidxd[EPB];       // 512 B
    __shared__ float lacc[MAXSPAN * OUTC];           // 5 KB bins

    const int lane = threadIdx.x;    // 0..63, one wave
    const int n    = lane & 15;
    const int q    = lane >> 4;

    const long b0   = (long)blockIdx.x * EPB;
    const long bEnd = (b0 + EPB < (long)E) ? (b0 + EPB) : (long)E;
    const bool full = (b0 + EPB <= (long)E);

    // ---- async stage: whole edge stream for this block, issued upfront ----
    if (full) {
        const char* efsrc = (const char*)edgefeats + (size_t)b0 * (EFN * 4);
        #pragma unroll
        for (int c = 0; c < 6; ++c)
            __builtin_amdgcn_global_load_lds(
                (const GLOBAL_AS unsigned int*)(efsrc + c * 1024 + lane * 16),
                (LDS_AS unsigned int*)((char*)sEF + c * 1024), 16, 0, 0);
        if (lane < 32) {   // half-chunk tail + index slabs (512 B each)
            __builtin_amdgcn_global_load_lds(
                (const GLOBAL_AS unsigned int*)(efsrc + 6144 + lane * 16),
                (LDS_AS unsigned int*)((char*)sEF + 6144), 16, 0, 0);
            __builtin_amdgcn_global_load_lds(
                (const GLOBAL_AS unsigned int*)((const char*)(idxn + b0) + lane * 16),
                (LDS_AS unsigned int*)sidxn, 16, 0, 0);
            __builtin_amdgcn_global_load_lds(
                (const GLOBAL_AS unsigned int*)((const char*)(idxd + b0) + lane * 16),
                (LDS_AS unsigned int*)sidxd, 16, 0, 0);
        }
    } else {
        // cold path (partial last block): clamped scalar staging
        const long mx = (long)E * EFN - 1;
        for (int i = lane; i < EPB * EFN; i += 64) {
            long gi = b0 * EFN + i;
            if (gi > mx) gi = mx;
            sEF[i] = edgefeats[gi];
        }
        const long Ec = (long)E - 1;
        for (int i = lane; i < EPB; i += 64) {
            long e = b0 + i;
            if (e > Ec) e = Ec;
            sidxn[i] = idxn[e];
            sidxd[i] = idxd[e];
        }
    }

    const int d_lo = idxd[b0];
    const int d_hi = idxd[bEnd - 1];
    const int span = d_hi - d_lo;   // < MAXSPAN by construction

    // ---- W2 B-fragments: 16 x dwordx4 from the L2-hot image -> 64 VGPRs ----
    H8 bfr[16];
    #pragma unroll
    for (int t = 0; t < 16; ++t)
        bfr[t].v = *(const half8v*)(wsB + ((size_t)(t * 64 + lane) * 8));

    // ---- zero bins ----
    #pragma unroll
    for (int it = 0; it < MAXSPAN * OUTC / 64; ++it) lacc[lane + it * 64] = 0.0f;

    // ---- per-lane constants: W1^T A-fragments, b1 C-init, b2 B-fragment ----
    half4v a1, a2;
    float4v c1, c2;
    #pragma unroll
    for (int jj = 0; jj < 4; ++jj) {
        const int f = q * 4 + jj;
        const bool ok = (f < EFN);
        a1[jj] = ok ? (_Float16)W1[f * HIDC + n]      : (_Float16)0.f;
        a2[jj] = ok ? (_Float16)W1[f * HIDC + 16 + n] : (_Float16)0.f;
        c1[jj] = b1[q * 4 + jj];
        c2[jj] = b1[16 + q * 4 + jj];
    }
    half8v bfragB2;
    #pragma unroll
    for (int j = 0; j < 8; ++j) {
        _Float16 val = (_Float16)0.f;
        if (q < 2) val = (_Float16)b2[(q * 8 + j) * 16 + n];
        bfragB2[j] = val;
    }

    const int f0i = (q < 3) ? (q * 4) : 9;  // q==3: feats 9..12, use last

    __syncthreads();   // drains global_load_lds (vmcnt) + LDS stores

    // ---- x-gather pipeline prologue: 2-deep, static slot names ----
    const int nd0 = sidxn[n];
    const int nd1 = sidxn[16 + n];
    half8v pxa0 = *(const half8v*)(xh + (size_t)nd0 * INC);
    half8v pxb0 = *(const half8v*)(xh + (size_t)nd0 * INC + 8);
    half8v pxa1 = *(const half8v*)(xh + (size_t)nd1 * INC);
    half8v pxb1 = *(const half8v*)(xh + (size_t)nd1 * INC + 8);
    __builtin_amdgcn_sched_barrier(0);   // pin prologue issue

    // ---- fully-unrolled 8-tile loop (static indices everywhere) ----
    #pragma unroll
    for (int t16 = 0; t16 < 8; ++t16) {
        const long base = b0 + (long)t16 * 16;
        const bool vM   = (base + n < (long)E);

        const half8v xA = (t16 & 1) ? pxa1 : pxa0;   // folds at compile time
        const half8v xB = (t16 & 1) ? pxb1 : pxb0;
        if (t16 < 6) {   // prefetch tile t16+2 into the just-freed slot
            const int ndn = sidxn[(t16 + 2) * 16 + n];
            if (t16 & 1) {
                pxa1 = *(const half8v*)(xh + (size_t)ndn * INC);
                pxb1 = *(const half8v*)(xh + (size_t)ndn * INC + 8);
            } else {
                pxa0 = *(const half8v*)(xh + (size_t)ndn * INC);
                pxb0 = *(const half8v*)(xh + (size_t)ndn * INC + 8);
            }
        }
        __builtin_amdgcn_sched_barrier(0);   // keep issue ahead of compute

        // destination offsets for this lane's 4 C-rows (sorted idxd)
        const int4 dd = *(const int4*)&sidxd[t16 * 16 + q * 4];

        // edgefeat fragment from the staged slab (LDS, ~120 cy, hidden)
        const float* efp = sEF + (size_t)(t16 * 16 + n) * EFN + f0i;
        const float e0 = efp[0], e1 = efp[1], e2 = efp[2], e3 = efp[3];

        // ---- compute tile t16 from resident registers ----
        H8 sa, sb_;
        sa.v = xA; sb_.v = xB;
        const half2v zz = {(_Float16)0.f, (_Float16)0.f};
        half2v selh[8];
        #pragma unroll
        for (int i = 0; i < 4; ++i) {
            selh[i]     = vM ? sa.h2[i]  : zz;
            selh[4 + i] = vM ? sb_.h2[i] : zz;
        }

        half4v efB;
        if (q < 3) {
            efB[0] = (_Float16)e0; efB[1] = (_Float16)e1;
            efB[2] = (_Float16)e2; efB[3] = (_Float16)e3;
        } else {
            efB[0] = (_Float16)e3; efB[1] = (_Float16)0.f;
            efB[2] = (_Float16)0.f; efB[3] = (_Float16)0.f;
        }

        // h^T = relu(W1^T @ EF^T + b1): lane holds hids {q*4+r, 16+q*4+r}
        const float4v hf1 = __builtin_amdgcn_mfma_f32_16x16x16f16(a1, efB, c1, 0, 0, 0);
        const float4v hf2 = __builtin_amdgcn_mfma_f32_16x16x16f16(a2, efB, c2, 0, 0, 0);

        H8 hu;   // hu half j <-> hid kappa(q,j); matches prep's image
        #pragma unroll
        for (int r = 0; r < 2; ++r) {
            half2v t1 = {(_Float16)fmaxf(hf1[2*r], 0.f), (_Float16)fmaxf(hf1[2*r+1], 0.f)};
            half2v t2 = {(_Float16)fmaxf(hf2[2*r], 0.f), (_Float16)fmaxf(hf2[2*r+1], 0.f)};
            hu.h2[r]     = t1;
            hu.h2[2 + r] = t2;
        }

        // ---- 16 W2 steps (B in registers) + 1 b2 step ----
        float4v acc = {0.f, 0.f, 0.f, 0.f};
        #pragma unroll
        for (int t = 0; t < 16; ++t) {
            _Float16 sv = (t & 1) ? selh[t >> 1][1] : selh[t >> 1][0];
            half2v sb = {sv, sv};
            H8 a;
            a.h2[0] = sb * hu.h2[0];
            a.h2[1] = sb * hu.h2[1];
            a.h2[2] = sb * hu.h2[2];
            a.h2[3] = sb * hu.h2[3];
            acc = __builtin_amdgcn_mfma_f32_16x16x32_f16(a.v, bfr[t].v, acc, 0, 0, 0);
        }
        {
            H8 a;
            #pragma unroll
            for (int j2 = 0; j2 < 4; ++j2) {
                a.h2[j2] = (q < 2) ? selh[q * 4 + j2] : zz;
            }
            acc = __builtin_amdgcn_mfma_f32_16x16x32_f16(a.v, bfragB2, acc, 0, 0, 0);
        }

        // ---- scatter into LDS bins; sorted => run-combine via dd.x==dd.w
        if (dd.x == dd.w) {
            atomicAdd(&lacc[(dd.x - d_lo) * OUTC + n],
                      acc[0] + acc[1] + acc[2] + acc[3]);
        } else {
            atomicAdd(&lacc[(dd.x - d_lo) * OUTC + n], acc[0]);
            atomicAdd(&lacc[(dd.y - d_lo) * OUTC + n], acc[1]);
            atomicAdd(&lacc[(dd.z - d_lo) * OUTC + n], acc[2]);
            atomicAdd(&lacc[(dd.w - d_lo) * OUTC + n], acc[3]);
        }
    }

    __syncthreads();   // order LDS atomics before the flush reads

    // ---- flush: fuse deg-division for complete segments -> out;
    //      boundary partials -> ws slots (no global atomics anywhere) ----
    const bool first_starts = (b0 == 0)        || (idxd[b0 - 1] != d_lo);
    const bool last_ends    = (bEnd == (long)E) || (idxd[bEnd]   != d_hi);

    for (int i = lane; i < (span + 1) * OUTC; i += 64) {
        const int u = i >> 4;
        const int o = i & 15;
        const int v = d_lo + u;
        const float bin = lacc[u * OUTC + o];
        const bool starts = (u > 0)    || first_starts;
        const bool ends   = (u < span) || last_ends;
        if (starts && ends) {
            const float dg = degs[v];
            out[(size_t)v * OUTC + o] = (dg > 0.0f) ? bin / dg : 0.0f;
        } else if (!starts) {
            wsPfirst[(size_t)blockIdx.x * OUTC + o] = bin;
        } else {
            wsPlast[(size_t)blockIdx.x * OUTC + o] = bin;
        }
    }
    if (lane == 0) {
        wsMeta[blockIdx.x * 4 + 0] = d_hi;
        wsMeta[blockIdx.x * 4 + 1] = last_ends ? 1 : 0;
        wsMeta[blockIdx.x * 4 + 2] =
            (((span > 0) || first_starts) && !last_ends) ? 1 : 0;
    }
}

// ---------------------------------------------------------------------------
// Fixup: (a) owner blocks walk their open run across following blocks and
// write the finalized node; (b) deg-0 nodes get zeros.
// ---------------------------------------------------------------------------
__global__ __launch_bounds__(256) void fixup_kernel(
    const float* __restrict__ degs,
    float*       __restrict__ out,
    const float* __restrict__ wsPfirst,
    const float* __restrict__ wsPlast,
    const int*   __restrict__ wsMeta,
    int N, int nblocks)
{
    const int t = blockIdx.x * 256 + threadIdx.x;

    if (t < nblocks && wsMeta[t * 4 + 2]) {
        const int v = wsMeta[t * 4 + 0];
        float tot[OUTC];
        #pragma unroll
        for (int o = 0; o < OUTC; ++o) tot[o] = wsPlast[(size_t)t * OUTC + o];
        for (int j = t + 1; j < nblocks; ++j) {
            #pragma unroll
            for (int o = 0; o < OUTC; ++o) tot[o] += wsPfirst[(size_t)j * OUTC + o];
            if (wsMeta[j * 4 + 0] != v || wsMeta[j * 4 + 1]) break;
        }
        const float dg = degs[v];   // v has edges => dg > 0
        #pragma unroll
        for (int o = 0; o < OUTC; ++o) out[(size_t)v * OUTC + o] = tot[o] / dg;
    }

    if (t < N && degs[t] == 0.0f) {
        float4* op = (float4*)(out + (size_t)t * OUTC);
        const float4 z = make_float4(0, 0, 0, 0);
        op[0] = z; op[1] = z; op[2] = z; op[3] = z;
    }
}

// ---------------------------------------------------------------------------
extern "C" void kernel_launch(void* const* d_in, const int* in_sizes, int n_in,
                              void* d_out, int out_size, void* d_ws, size_t ws_size,
                              hipStream_t stream)
{
    const float* x         = (const float*)d_in[0];
    const float* edgefeats = (const float*)d_in[1];
    const float* W1        = (const float*)d_in[2];
    const float* b1        = (const float*)d_in[3];
    const float* W2        = (const float*)d_in[4];
    const float* b2        = (const float*)d_in[5];
    const int*   idxn      = (const int*)d_in[6];
    const int*   idxd      = (const int*)d_in[7];
    const float* degs      = (const float*)d_in[8];

    const int E = in_sizes[6];
    const int N = in_sizes[8];
    const int nblocks = (E + EPB - 1) / EPB;
    const int nh = N * INC;

    // workspace layout: wsB (16 KB) | wsXh (N*16 f16) | ws slots
    _Float16* wsB  = (_Float16*)d_ws;
    _Float16* wsXh = (_Float16*)((char*)d_ws + 16384);
    size_t xh_bytes = ((size_t)nh * 2 + 255) & ~(size_t)255;
    float* wsPfirst = (float*)((char*)d_ws + 16384 + xh_bytes);
    float* wsPlast  = wsPfirst + (size_t)nblocks * OUTC;
    int*   wsMeta   = (int*)(wsPlast + (size_t)nblocks * OUTC);

    const int xhblocks = (nh / 8 + 255) / 256;
    prep<<<32 + xhblocks, 256, 0, stream>>>(W2, x, wsB, wsXh, nh);

    edge_kernel<<<nblocks, 64, 0, stream>>>(wsXh, edgefeats, W1, b1, b2,
                                            idxn, idxd, degs, wsB, (float*)d_out,
                                            wsPfirst, wsPlast, wsMeta, E);

    const int fthreads = (N > nblocks) ? N : nblocks;
    fixup_kernel<<<(fthreads + 255) / 256, 256, 0, stream>>>(
        degs, (float*)d_out, wsPfirst, wsPlast, wsMeta, N, nblocks);
}